// Round 12
// baseline (276.907 us; speedup 1.0000x reference)
//
#include <hip/hip_runtime.h>
#include <hip/hip_bf16.h>
#include <stdint.h>

typedef short short8 __attribute__((ext_vector_type(8)));
typedef float f32x4 __attribute__((ext_vector_type(4)));
typedef unsigned short ushort4_t __attribute__((ext_vector_type(4)));
typedef unsigned short ushort8_t __attribute__((ext_vector_type(8)));

#define S_LEN 2048
#define NQKV 1536
#define DMODEL 512

// ======== DIAGNOSTIC ROUND: in-kernel REP loops (idempotent) to surface ======
// ======== per-kernel dur & counters in rocprof top-5. Revert next round. =====

__device__ inline unsigned short f2bf(float f) {
  unsigned int u = __float_as_uint(f);
  unsigned int r = (u + 0x7FFFu + ((u >> 16) & 1u)) >> 16;
  return (unsigned short)r;
}

// async global->LDS, 16B per lane. LDS dest must be linear in lane order.
__device__ __forceinline__ void gll16(const unsigned short* g, unsigned short* l) {
  __builtin_amdgcn_global_load_lds(
      (const __attribute__((address_space(1))) unsigned int*)g,
      (__attribute__((address_space(3))) unsigned int*)l, 16, 0, 0);
}

// ---------------- fused prep: x->bf16, weight transposes, pad zeroing --------
__global__ __launch_bounds__(256) void k_prep(const float* __restrict__ x,
                                              unsigned short* __restrict__ xb,
                                              const float* __restrict__ w1,
                                              unsigned short* __restrict__ o1,
                                              const float* __restrict__ w2,
                                              unsigned short* __restrict__ o2,
                                              unsigned short* __restrict__ Kp,
                                              unsigned short* __restrict__ Vp) {
  __shared__ float T[32][33];
  const int bid0 = blockIdx.x;
  const int t = threadIdx.x;
  for (int rep = 0; rep < 24; ++rep) {
    __syncthreads();
    int bid = bid0;
    if (bid < 1024) {
      int i = (bid * 256 + t) * 8;
      float4 a = *(const float4*)(x + i);
      float4 b = *(const float4*)(x + i + 4);
      ushort8_t o;
      o[0] = f2bf(a.x); o[1] = f2bf(a.y); o[2] = f2bf(a.z); o[3] = f2bf(a.w);
      o[4] = f2bf(b.x); o[5] = f2bf(b.y); o[6] = f2bf(b.z); o[7] = f2bf(b.w);
      *(ushort8_t*)(xb + i) = o;
      continue;
    }
    if (bid >= 2048) {  // pad zeroing
      int p = bid - 2048;
      ushort8_t z = {};
      if (p < 16) {
        unsigned short* dst = Kp + (size_t)p * 2112 * 64;
#pragma unroll
        for (int i = 0; i < 2; i++) {
          int s = t + 256 * i;
          int row = s >> 3, c = s & 7;
          int r2 = row < 32 ? row : row - 32 + 2080;
          *(ushort8_t*)&dst[r2 * 64 + c * 8] = z;
        }
      } else {
        unsigned short* dst = Vp + (size_t)(p - 16) * 64 * 2112;
#pragma unroll
        for (int i = 0; i < 2; i++) {
          int s = t + 256 * i;
          int d = s >> 3, side = (s >> 2) & 1, c = s & 3;
          *(ushort8_t*)&dst[(size_t)d * 2112 + side * 2080 + c * 8] = z;
        }
      }
      continue;
    }
    bid -= 1024;
    int bx = bid & 63, byy = bid >> 6;
    const float* w; unsigned short* o; int cols;
    if (bx < 48) { w = w1; o = o1; cols = 1536; }
    else         { w = w2; o = o2; cols = 512; bx -= 48; }
    int r0 = byy * 32, c0 = bx * 32;
    int tr = t / 32, tc = t % 32;
#pragma unroll
    for (int i = 0; i < 4; i++) {
      int r = tr + i * 8;
      T[r][tc] = w[(size_t)(r0 + r) * cols + c0 + tc];
    }
    __syncthreads();
#pragma unroll
    for (int i = 0; i < 4; i++) {
      int rr = tr + i * 8;
      o[(size_t)(c0 + rr) * 512 + r0 + tc] = f2bf(T[tc][rr]);
    }
  }
}

// ---------------- GEMM (REP-instrumented; structure = round 11) --------------
template <int BM, int BN, int MODE, int REP>
__global__ __launch_bounds__(256) void k_gemm(const unsigned short* __restrict__ A,
                                              const unsigned short* __restrict__ Bt,
                                              void* __restrict__ Cout,
                                              const float* __restrict__ bias,
                                              unsigned short* __restrict__ qs,
                                              unsigned short* __restrict__ kp,
                                              unsigned short* __restrict__ vp,
                                              int M, int N, int K) {
  constexpr int MR = BM / 32, NR = BN / 32;
  constexpr int CA = BM / 32, CB = BN / 32;
  constexpr int STAGE_SH = 2 * (BM + BN) * 64;
  constexpr int BOUNCE_SH = MODE == 0 ? BM * BN * 2 : BM * BN;
  constexpr int SMEM_SH = STAGE_SH > BOUNCE_SH ? STAGE_SH : BOUNCE_SH;
  __shared__ __align__(16) unsigned short smem[SMEM_SH];
  const int ASZ = BM * 64, BOFF = 2 * BM * 64, BSZ = BN * 64;

  const int t = threadIdx.x, lane = t & 63, wid = t >> 6;
  const int m0 = blockIdx.y * BM, n0 = blockIdx.x * BN;
  const int wm = (wid >> 1) * (BM / 2), wn = (wid & 1) * (BN / 2);
  const int lr = lane & 15, lg = lane >> 4;
  const unsigned short* Ab = A + (size_t)m0 * K;
  const unsigned short* Bb = Bt + (size_t)n0 * K;

  const int NT = K / 64;
  auto stage = [&](int buf, int kt) {
#pragma unroll
    for (int c = 0; c < CA; c++) {
      int f = t + 256 * c;
      int row = f >> 3, ch = f & 7;
      gll16(Ab + (size_t)row * K + kt + ((ch ^ (row & 7)) << 3),
            &smem[buf * ASZ + f * 8]);
    }
#pragma unroll
    for (int c = 0; c < CB; c++) {
      int f = t + 256 * c;
      int row = f >> 3, ch = f & 7;
      gll16(Bb + (size_t)row * K + kt + ((ch ^ (row & 7)) << 3),
            &smem[BOFF + buf * BSZ + f * 8]);
    }
  };

  for (int rep = 0; rep < REP; ++rep) {
    __syncthreads();
    f32x4 acc[MR][NR] = {};
    stage(0, 0);
    int buf = 0;
    for (int it = 0; it < NT; ++it) {
      __syncthreads();
      if (it + 1 < NT) stage(buf ^ 1, (it + 1) * 64);
      const unsigned short* Ap = &smem[buf * ASZ];
      const unsigned short* Bp = &smem[BOFF + buf * BSZ];
#pragma unroll
      for (int sl = 0; sl < 2; sl++) {
        const int cs = sl * 4 + lg;
        short8 af[MR], bfv[NR];
#pragma unroll
        for (int i = 0; i < MR; i++) {
          int row = wm + i * 16 + lr;
          af[i] = *(const short8*)&Ap[row * 64 + ((cs ^ (row & 7)) << 3)];
        }
#pragma unroll
        for (int i = 0; i < NR; i++) {
          int row = wn + i * 16 + lr;
          bfv[i] = *(const short8*)&Bp[row * 64 + ((cs ^ (row & 7)) << 3)];
        }
#pragma unroll
        for (int mi = 0; mi < MR; mi++)
#pragma unroll
          for (int ni = 0; ni < NR; ni++)
            acc[mi][ni] = __builtin_amdgcn_mfma_f32_16x16x32_bf16(af[mi], bfv[ni], acc[mi][ni], 0, 0, 0);
      }
      buf ^= 1;
    }

    if (MODE == 0) {
      __syncthreads();
      float* ft = (float*)smem;
#pragma unroll
      for (int mi = 0; mi < MR; mi++)
#pragma unroll
        for (int ni = 0; ni < NR; ni++)
#pragma unroll
          for (int j = 0; j < 4; j++)
            ft[(wm + mi * 16 + lg * 4 + j) * BN + wn + ni * 16 + lr] = acc[mi][ni][j];
      __syncthreads();
#pragma unroll
      for (int i = 0; i < BM * BN / 1024; i++) {
        int s = t + 256 * i;
        int row = s / (BN / 4), ch = s % (BN / 4);
        float4 v = *(const float4*)&ft[row * BN + ch * 4];
        float4 bv = *(const float4*)&bias[n0 + ch * 4];
        v.x += bv.x; v.y += bv.y; v.z += bv.z; v.w += bv.w;
        *(float4*)&((float*)Cout)[(size_t)(m0 + row) * N + n0 + ch * 4] = v;
      }
    } else {
      __syncthreads();
#pragma unroll
      for (int mi = 0; mi < MR; mi++)
#pragma unroll
        for (int ni = 0; ni < NR; ni++)
#pragma unroll
          for (int j = 0; j < 4; j++) {
            int row = wm + mi * 16 + lg * 4 + j;
            int col = wn + ni * 16 + lr;
            smem[row * 64 + (((col >> 3) ^ ((row >> 3) & 7)) << 3) + (col & 7)] =
                f2bf(acc[mi][ni][j]);
          }
      __syncthreads();

      const int b_ = m0 >> 11;
      const int posb = m0 & 2047;
      const int h = n0 / 192, seg = (n0 % 192) >> 6;
      if (seg < 2) {
        unsigned short* dst = (seg == 0)
            ? qs + ((size_t)(b_ * 8 + h) * 2048 + posb) * 64
            : kp + ((size_t)(b_ * 8 + h) * 2112 + 32 + posb) * 64;
#pragma unroll
        for (int i = 0; i < BM / 32; i++) {
          int s = t + 256 * i;
          int row = s >> 3, ch = s & 7;
          int src = row * 64 + ((ch ^ ((row >> 3) & 7)) << 3);
          *(ushort8_t*)&dst[s * 8] = *(const ushort8_t*)&smem[src];
        }
      } else {
        unsigned short* dst = vp + (size_t)(b_ * 8 + h) * 64 * 2112;
#pragma unroll
        for (int i = 0; i < BM / 32; i++) {
          int s = t + 256 * i;
          int dl = s / (BM / 8), pc = s % (BM / 8);
          ushort8_t v;
#pragma unroll
          for (int j = 0; j < 8; j++) {
            int row = pc * 8 + j;
            v[j] = smem[row * 64 + ((((dl >> 3) ^ (pc & 7)) << 3)) + (dl & 7)];
          }
          *(ushort8_t*)&dst[(size_t)dl * 2112 + 32 + posb + pc * 8] = v;
        }
      }
    }
  }
}

// ---------------- windowed attention (REP-instrumented; round-11 structure) --
__global__ __launch_bounds__(512) void k_attn(const unsigned short* __restrict__ Qs,
                                              const unsigned short* __restrict__ Kp,
                                              const unsigned short* __restrict__ Vp,
                                              unsigned short* __restrict__ attnb) {
  __shared__ __align__(16) unsigned short Kt[192 * 64];
  __shared__ __align__(16) unsigned short Vt[64 * 256];
  __shared__ __align__(16) unsigned short Qt[128 * 64];
  const int t = threadIdx.x, lane = t & 63, w = t >> 6;
  const int blk = blockIdx.x;
  const int sbi = blk & 15, h = (blk >> 4) & 7, b = blk >> 7;
  const int sb = sbi * 128;
  const int bh = b * 8 + h;
  const int lr = lane & 15, lg = lane >> 4;

  for (int rep = 0; rep < 16; ++rep) {
    __syncthreads();
    {
      const unsigned short* src = Kp + ((size_t)bh * 2112 + sb) * 64;
#pragma unroll
      for (int i = 0; i < 3; i++) {
        int s = t + 512 * i, row = s >> 3, c = s & 7;
        gll16(src + row * 64 + (c ^ (row & 7)) * 8, &Kt[s * 8]);
      }
    }
    {
      const unsigned short* src = Vp + (size_t)bh * 64 * 2112 + sb;
#pragma unroll
      for (int i = 0; i < 4; i++) {
        int s = t + 512 * i, d = s >> 5, c = s & 31;
        gll16(src + (size_t)d * 2112 + (c ^ (d & 7)) * 8, &Vt[s * 8]);
      }
    }
    {
      const unsigned short* src = Qs + ((size_t)bh * 2048 + sb) * 64;
#pragma unroll
      for (int i = 0; i < 2; i++) {
        int s = t + 512 * i, row = s >> 3, c = s & 7;
        gll16(src + row * 64 + (c ^ (row & 7)) * 8, &Qt[s * 8]);
      }
    }
    __syncthreads();

    const int sw = (lr & 7) << 3;

    short8 qb[2];
#pragma unroll
    for (int ks = 0; ks < 2; ks++)
      qb[ks] = *(const short8*)&Qt[(w * 16 + lr) * 64 + ((ks * 32 + lg * 8) ^ sw)];

    f32x4 sc[5] = {};
#pragma unroll
    for (int ct = 0; ct < 5; ct++) {
#pragma unroll
      for (int ks = 0; ks < 2; ks++) {
        short8 ka = *(const short8*)&Kt[(w * 16 + ct * 16 + lr) * 64 + ((ks * 32 + lg * 8) ^ sw)];
        sc[ct] = __builtin_amdgcn_mfma_f32_16x16x32_bf16(ka, qb[ks], sc[ct], 0, 0, 0);
      }
    }

    float mx = -1e30f;
#pragma unroll
    for (int ct = 0; ct < 5; ct++)
#pragma unroll
      for (int j = 0; j < 4; j++) {
        int c2 = ct * 16 + lg * 4 + j;
        sc[ct][j] = (c2 >= lr && c2 <= lr + 64) ? sc[ct][j] * 0.125f : -1e30f;
        mx = fmaxf(mx, sc[ct][j]);
      }
    mx = fmaxf(mx, __shfl_xor(mx, 16, 64));
    mx = fmaxf(mx, __shfl_xor(mx, 32, 64));

    float pn[5][4];
    float sum = 0.0f;
#pragma unroll
    for (int ct = 0; ct < 5; ct++)
#pragma unroll
      for (int j = 0; j < 4; j++) {
        pn[ct][j] = __expf(sc[ct][j] - mx);
        sum += pn[ct][j];
      }
    sum += __shfl_xor(sum, 16, 64);
    sum += __shfl_xor(sum, 32, 64);
    float inv = 1.0f / sum;

    unsigned int w01[5], w23[5];
#pragma unroll
    for (int ct = 0; ct < 5; ct++) {
      w01[ct] = (unsigned int)f2bf(pn[ct][0] * inv) | ((unsigned int)f2bf(pn[ct][1] * inv) << 16);
      w23[ct] = (unsigned int)f2bf(pn[ct][2] * inv) | ((unsigned int)f2bf(pn[ct][3] * inv) << 16);
    }

    f32x4 oa[4] = {};
    const int h2 = lg & 1, tl = lg >> 1;
    const int sA = 32 * h2 + lr, sB = sA + 16;
#pragma unroll
    for (int ks = 0; ks < 3; ks++) {
      const int T0 = 2 * ks;
      const int T1 = (2 * ks + 1 < 5) ? (2 * ks + 1) : 4;
      unsigned int a0 = __shfl((int)w01[T0], sA, 64), a1 = __shfl((int)w23[T0], sA, 64);
      unsigned int a2 = __shfl((int)w01[T0], sB, 64), a3 = __shfl((int)w23[T0], sB, 64);
      unsigned int b0 = __shfl((int)w01[T1], sA, 64), b1 = __shfl((int)w23[T1], sA, 64);
      unsigned int b2 = __shfl((int)w01[T1], sB, 64), b3 = __shfl((int)w23[T1], sB, 64);
      union { unsigned int u[4]; short8 v; } pb;
      pb.u[0] = tl ? b0 : a0;
      pb.u[1] = tl ? b1 : a1;
      pb.u[2] = tl ? b2 : a2;
      pb.u[3] = tl ? b3 : a3;
      if (ks == 2 && tl) { pb.u[0] = 0; pb.u[1] = 0; pb.u[2] = 0; pb.u[3] = 0; }
      int pofl = w * 16 + ks * 32 + lg * 8;
#pragma unroll
      for (int nt = 0; nt < 4; nt++) {
        short8 va = *(const short8*)&Vt[(nt * 16 + lr) * 256 + (pofl ^ sw)];
        oa[nt] = __builtin_amdgcn_mfma_f32_16x16x32_bf16(va, pb.v, oa[nt], 0, 0, 0);
      }
    }

    const int s0 = sb + w * 16;
#pragma unroll
    for (int nt = 0; nt < 4; nt++) {
      ushort4_t o;
#pragma unroll
      for (int j = 0; j < 4; j++) o[j] = f2bf(oa[nt][j]);
      *(ushort4_t*)&attnb[((size_t)b * S_LEN + s0 + lr) * DMODEL + h * 64 + nt * 16 + lg * 4] = o;
    }
  }
}

// ---------------- launch ----------------
extern "C" void kernel_launch(void* const* d_in, const int* in_sizes, int n_in,
                              void* d_out, int out_size, void* d_ws, size_t ws_size,
                              hipStream_t stream) {
  const float* x    = (const float*)d_in[0];
  const float* Wqkv = (const float*)d_in[1];
  const float* Wout = (const float*)d_in[2];
  const float* bout = (const float*)d_in[3];
  char* ws = (char*)d_ws;
  unsigned short* xb    = (unsigned short*)(ws + 0);
  unsigned short* wqkvt = (unsigned short*)(ws + 4194304);
  unsigned short* woutt = (unsigned short*)(ws + 5767168);
  unsigned short* Qs    = (unsigned short*)(ws + 6291456);
  unsigned short* Kp    = (unsigned short*)(ws + 10485760);
  unsigned short* Vp    = (unsigned short*)(ws + 14811136);
  unsigned short* attnb = (unsigned short*)(ws + 19922944);

  hipLaunchKernelGGL(k_prep, dim3(2080), dim3(256), 0, stream,
                     x, xb, Wqkv, wqkvt, Wout, woutt, Kp, Vp);
  hipLaunchKernelGGL((k_gemm<128, 64, 1, 12>), dim3(24, 32), dim3(256), 0, stream,
                     xb, wqkvt, nullptr, (const float*)nullptr, Qs, Kp, Vp, 4096, 1536, 512);
  hipLaunchKernelGGL(k_attn, dim3(256), dim3(512), 0, stream, Qs, Kp, Vp, attnb);
  hipLaunchKernelGGL((k_gemm<64, 64, 0, 16>), dim3(8, 64), dim3(256), 0, stream,
                     attnb, woutt, d_out, bout,
                     (unsigned short*)nullptr, (unsigned short*)nullptr,
                     (unsigned short*)nullptr, 4096, 512, 512);
}

// Round 13
// 145.516 us; speedup vs baseline: 1.9029x; 1.9029x over previous
//
#include <hip/hip_runtime.h>
#include <hip/hip_bf16.h>
#include <hip/hip_cooperative_groups.h>
#include <stdint.h>

namespace cg = cooperative_groups;

typedef short short8 __attribute__((ext_vector_type(8)));
typedef float f32x4 __attribute__((ext_vector_type(4)));
typedef unsigned short ushort4_t __attribute__((ext_vector_type(4)));
typedef unsigned short ushort8_t __attribute__((ext_vector_type(8)));

#define S_LEN 2048
#define NQKV 1536
#define DMODEL 512

__device__ inline unsigned short f2bf(float f) {
  unsigned int u = __float_as_uint(f);
  unsigned int r = (u + 0x7FFFu + ((u >> 16) & 1u)) >> 16;
  return (unsigned short)r;
}

// async global->LDS, 16B per lane. LDS dest must be linear in lane order.
__device__ __forceinline__ void gll16(const unsigned short* g, unsigned short* l) {
  __builtin_amdgcn_global_load_lds(
      (const __attribute__((address_space(1))) unsigned int*)g,
      (__attribute__((address_space(3))) unsigned int*)l, 16, 0, 0);
}

// ===== single cooperative kernel: prep | gemm1 | attn | gemm2, 3 grid syncs ==
// 256 blocks x 768 threads (3 virtual 256-thr sub-blocks); LDS 144 KB.
__global__ __launch_bounds__(768, 3) void k_mega(
    const float* __restrict__ x, const float* __restrict__ w1,
    const float* __restrict__ w2, const float* __restrict__ bias,
    unsigned short* __restrict__ xb, unsigned short* __restrict__ wqkvt,
    unsigned short* __restrict__ woutt, unsigned short* __restrict__ Qs,
    unsigned short* __restrict__ Kp, unsigned short* __restrict__ Vp,
    unsigned short* __restrict__ attnb, float* __restrict__ out) {
  __shared__ __align__(16) unsigned short smem[73728];  // 144 KB
  cg::grid_group grid = cg::this_grid();
  const int blk = blockIdx.x;   // 0..255
  const int t = threadIdx.x;    // 0..767
  const int sub = t >> 8;       // virtual 256-thr sub-block 0..2
  const int tl = t & 255;
  const int lane = tl & 63, wid = tl >> 6;
  const int lr = lane & 15, lg = lane >> 4;

  // ================= Phase 0: prep (uniform 2 barriers per iteration) =======
  {
    float(*T)[33] = (float(*)[33])(smem + sub * 4096);
    for (int it = 0; it < 3; ++it) {
      int vb = blk * 3 + sub + it * 768;
      int kind = (vb < 1024) ? 0 : (vb < 2048) ? 1 : (vb < 2080) ? 2 : -1;
      const float* w = nullptr; unsigned short* o = nullptr;
      int bx = 0, byy = 0, cols = 0;
      if (kind == 0) {
        int i = (vb * 256 + tl) * 8;
        float4 a = *(const float4*)(x + i);
        float4 b = *(const float4*)(x + i + 4);
        ushort8_t ov;
        ov[0] = f2bf(a.x); ov[1] = f2bf(a.y); ov[2] = f2bf(a.z); ov[3] = f2bf(a.w);
        ov[4] = f2bf(b.x); ov[5] = f2bf(b.y); ov[6] = f2bf(b.z); ov[7] = f2bf(b.w);
        *(ushort8_t*)(xb + i) = ov;
      } else if (kind == 2) {
        int p = vb - 2048;
        ushort8_t z = {};
        if (p < 16) {
          unsigned short* dst = Kp + (size_t)p * 2112 * 64;
#pragma unroll
          for (int i = 0; i < 2; i++) {
            int s = tl + 256 * i;
            int row = s >> 3, c = s & 7;
            int r2 = row < 32 ? row : row - 32 + 2080;
            *(ushort8_t*)&dst[r2 * 64 + c * 8] = z;
          }
        } else {
          unsigned short* dst = Vp + (size_t)(p - 16) * 64 * 2112;
#pragma unroll
          for (int i = 0; i < 2; i++) {
            int s = tl + 256 * i;
            int d = s >> 3, side = (s >> 2) & 1, c = s & 3;
            *(ushort8_t*)&dst[(size_t)d * 2112 + side * 2080 + c * 8] = z;
          }
        }
      } else if (kind == 1) {
        int v2 = vb - 1024;
        bx = v2 & 63; byy = v2 >> 6;
        if (bx < 48) { w = w1; o = wqkvt; cols = 1536; }
        else         { w = w2; o = woutt; cols = 512; bx -= 48; }
        int r0 = byy * 32, c0 = bx * 32;
        int tr = tl / 32, tc = tl % 32;
#pragma unroll
        for (int i = 0; i < 4; i++) {
          int r = tr + i * 8;
          T[r][tc] = w[(size_t)(r0 + r) * cols + c0 + tc];
        }
      }
      __syncthreads();
      if (kind == 1) {
        int r0 = byy * 32, c0 = bx * 32;
        int tr = tl / 32, tc = tl % 32;
#pragma unroll
        for (int i = 0; i < 4; i++) {
          int rr = tr + i * 8;
          o[(size_t)(c0 + rr) * 512 + r0 + tc] = f2bf(T[tc][rr]);
        }
      }
      __syncthreads();
    }
  }
  grid.sync();

  // ================= Phase 1: gemm1 — one 128x64 tile per sub-block =========
  {
    unsigned short* vs = smem + sub * 24576;  // 48 KB region
    const int ASZ = 8192, BOFF = 16384, BSZ = 4096;
    const int vb = blk * 3 + sub;             // 0..767 tiles (24 n x 32 m)
    const int m0 = (vb / 24) * 128, n0 = (vb % 24) * 64;
    const int wm = (wid >> 1) * 64, wn = (wid & 1) * 32;
    const unsigned short* Ab = xb + (size_t)m0 * 512;
    const unsigned short* Bb = wqkvt + (size_t)n0 * 512;
    f32x4 acc[4][2] = {};

    auto stage = [&](int buf, int kt) {
#pragma unroll
      for (int c = 0; c < 4; c++) {
        int f = tl + 256 * c;
        int row = f >> 3, ch = f & 7;
        gll16(Ab + (size_t)row * 512 + kt + ((ch ^ (row & 7)) << 3),
              &vs[buf * ASZ + f * 8]);
      }
#pragma unroll
      for (int c = 0; c < 2; c++) {
        int f = tl + 256 * c;
        int row = f >> 3, ch = f & 7;
        gll16(Bb + (size_t)row * 512 + kt + ((ch ^ (row & 7)) << 3),
              &vs[BOFF + buf * BSZ + f * 8]);
      }
    };

    stage(0, 0);
    int buf = 0;
    for (int it = 0; it < 8; ++it) {
      __syncthreads();
      if (it + 1 < 8) stage(buf ^ 1, (it + 1) * 64);
      const unsigned short* Ap = &vs[buf * ASZ];
      const unsigned short* Bp = &vs[BOFF + buf * BSZ];
#pragma unroll
      for (int sl = 0; sl < 2; sl++) {
        const int cs = sl * 4 + lg;
        short8 af[4], bfv[2];
#pragma unroll
        for (int i = 0; i < 4; i++) {
          int row = wm + i * 16 + lr;
          af[i] = *(const short8*)&Ap[row * 64 + ((cs ^ (row & 7)) << 3)];
        }
#pragma unroll
        for (int i = 0; i < 2; i++) {
          int row = wn + i * 16 + lr;
          bfv[i] = *(const short8*)&Bp[row * 64 + ((cs ^ (row & 7)) << 3)];
        }
#pragma unroll
        for (int mi = 0; mi < 4; mi++)
#pragma unroll
          for (int ni = 0; ni < 2; ni++)
            acc[mi][ni] = __builtin_amdgcn_mfma_f32_16x16x32_bf16(af[mi], bfv[ni], acc[mi][ni], 0, 0, 0);
      }
      buf ^= 1;
    }

    // swizzled bf16 bounce [128][64] + de-interleaved contiguous stores
    __syncthreads();
#pragma unroll
    for (int mi = 0; mi < 4; mi++)
#pragma unroll
      for (int ni = 0; ni < 2; ni++)
#pragma unroll
        for (int j = 0; j < 4; j++) {
          int row = wm + mi * 16 + lg * 4 + j;
          int col = wn + ni * 16 + lr;
          vs[row * 64 + (((col >> 3) ^ ((row >> 3) & 7)) << 3) + (col & 7)] =
              f2bf(acc[mi][ni][j]);
        }
    __syncthreads();

    const int b_ = m0 >> 11;
    const int posb = m0 & 2047;
    const int h = n0 / 192, seg = (n0 % 192) >> 6;
    if (seg < 2) {
      unsigned short* dst = (seg == 0)
          ? Qs + ((size_t)(b_ * 8 + h) * 2048 + posb) * 64
          : Kp + ((size_t)(b_ * 8 + h) * 2112 + 32 + posb) * 64;
#pragma unroll
      for (int i = 0; i < 4; i++) {
        int s = tl + 256 * i;
        int row = s >> 3, ch = s & 7;
        int src = row * 64 + ((ch ^ ((row >> 3) & 7)) << 3);
        *(ushort8_t*)&dst[s * 8] = *(const ushort8_t*)&vs[src];
      }
    } else {
      unsigned short* dst = Vp + (size_t)(b_ * 8 + h) * 64 * 2112;
#pragma unroll
      for (int i = 0; i < 4; i++) {
        int s = tl + 256 * i;
        int dl = s >> 4, pc = s & 15;
        ushort8_t v;
#pragma unroll
        for (int j = 0; j < 8; j++) {
          int row = pc * 8 + j;
          v[j] = vs[row * 64 + ((((dl >> 3) ^ (pc & 7)) << 3)) + (dl & 7)];
        }
        *(ushort8_t*)&dst[(size_t)dl * 2112 + 32 + posb + pc * 8] = v;
      }
    }
  }
  grid.sync();

  // ================= Phase 2: attn — (b,h,128q) per block ===================
  {
    unsigned short* Kt = smem;            // 192*64
    unsigned short* Vt = smem + 12288;    // 64*256
    unsigned short* Qt = smem + 28672;    // 128*64
    const int h = blk & 7, sbi = (blk >> 3) & 15, b = blk >> 7;  // gemm1-aligned
    const int sb = sbi * 128, bh = b * 8 + h;
    const int w = t >> 6;                 // 0..11; waves 8..11 idle in compute
    const int lane6 = t & 63;
    const int alr = lane6 & 15, alg = lane6 >> 4;

    {
      const unsigned short* src = Kp + ((size_t)bh * 2112 + sb) * 64;
#pragma unroll
      for (int i = 0; i < 2; i++) {
        int s = t + 768 * i;              // 1536 chunks exact
        int row = s >> 3, c = s & 7;
        gll16(src + row * 64 + (c ^ (row & 7)) * 8, &Kt[s * 8]);
      }
    }
    {
      const unsigned short* src = Vp + (size_t)bh * 64 * 2112 + sb;
#pragma unroll
      for (int i = 0; i < 3; i++) {
        int s = t + 768 * i;
        if (s < 2048) {
          int d = s >> 5, c = s & 31;
          gll16(src + (size_t)d * 2112 + (c ^ (d & 7)) * 8, &Vt[s * 8]);
        }
      }
    }
    {
      const unsigned short* src = Qs + ((size_t)bh * 2048 + sb) * 64;
#pragma unroll
      for (int i = 0; i < 2; i++) {
        int s = t + 768 * i;
        if (s < 1024) {
          int row = s >> 3, c = s & 7;
          gll16(src + row * 64 + (c ^ (row & 7)) * 8, &Qt[s * 8]);
        }
      }
    }
    __syncthreads();

    if (w < 8) {
      const int sw = (alr & 7) << 3;

      short8 qb[2];
#pragma unroll
      for (int ks = 0; ks < 2; ks++)
        qb[ks] = *(const short8*)&Qt[(w * 16 + alr) * 64 + ((ks * 32 + alg * 8) ^ sw)];

      f32x4 sc[5] = {};
#pragma unroll
      for (int ct = 0; ct < 5; ct++) {
#pragma unroll
        for (int ks = 0; ks < 2; ks++) {
          short8 ka = *(const short8*)&Kt[(w * 16 + ct * 16 + alr) * 64 + ((ks * 32 + alg * 8) ^ sw)];
          sc[ct] = __builtin_amdgcn_mfma_f32_16x16x32_bf16(ka, qb[ks], sc[ct], 0, 0, 0);
        }
      }

      float mx = -1e30f;
#pragma unroll
      for (int ct = 0; ct < 5; ct++)
#pragma unroll
        for (int j = 0; j < 4; j++) {
          int c2 = ct * 16 + alg * 4 + j;
          sc[ct][j] = (c2 >= alr && c2 <= alr + 64) ? sc[ct][j] * 0.125f : -1e30f;
          mx = fmaxf(mx, sc[ct][j]);
        }
      mx = fmaxf(mx, __shfl_xor(mx, 16, 64));
      mx = fmaxf(mx, __shfl_xor(mx, 32, 64));

      float pn[5][4];
      float sum = 0.0f;
#pragma unroll
      for (int ct = 0; ct < 5; ct++)
#pragma unroll
        for (int j = 0; j < 4; j++) {
          pn[ct][j] = __expf(sc[ct][j] - mx);
          sum += pn[ct][j];
        }
      sum += __shfl_xor(sum, 16, 64);
      sum += __shfl_xor(sum, 32, 64);
      float inv = 1.0f / sum;

      unsigned int w01[5], w23[5];
#pragma unroll
      for (int ct = 0; ct < 5; ct++) {
        w01[ct] = (unsigned int)f2bf(pn[ct][0] * inv) | ((unsigned int)f2bf(pn[ct][1] * inv) << 16);
        w23[ct] = (unsigned int)f2bf(pn[ct][2] * inv) | ((unsigned int)f2bf(pn[ct][3] * inv) << 16);
      }

      f32x4 oa[4] = {};
      const int h2 = alg & 1, tsel = alg >> 1;
      const int sA = 32 * h2 + alr, sB = sA + 16;
#pragma unroll
      for (int ks = 0; ks < 3; ks++) {
        const int T0 = 2 * ks;
        const int T1 = (2 * ks + 1 < 5) ? (2 * ks + 1) : 4;
        unsigned int a0 = __shfl((int)w01[T0], sA, 64), a1 = __shfl((int)w23[T0], sA, 64);
        unsigned int a2 = __shfl((int)w01[T0], sB, 64), a3 = __shfl((int)w23[T0], sB, 64);
        unsigned int b0 = __shfl((int)w01[T1], sA, 64), b1 = __shfl((int)w23[T1], sA, 64);
        unsigned int b2 = __shfl((int)w01[T1], sB, 64), b3 = __shfl((int)w23[T1], sB, 64);
        union { unsigned int u[4]; short8 v; } pb;
        pb.u[0] = tsel ? b0 : a0;
        pb.u[1] = tsel ? b1 : a1;
        pb.u[2] = tsel ? b2 : a2;
        pb.u[3] = tsel ? b3 : a3;
        if (ks == 2 && tsel) { pb.u[0] = 0; pb.u[1] = 0; pb.u[2] = 0; pb.u[3] = 0; }
        int pofl = w * 16 + ks * 32 + alg * 8;
#pragma unroll
        for (int nt = 0; nt < 4; nt++) {
          short8 va = *(const short8*)&Vt[(nt * 16 + alr) * 256 + (pofl ^ sw)];
          oa[nt] = __builtin_amdgcn_mfma_f32_16x16x32_bf16(va, pb.v, oa[nt], 0, 0, 0);
        }
      }

      const int s0 = sb + w * 16;
#pragma unroll
      for (int nt = 0; nt < 4; nt++) {
        ushort4_t o;
#pragma unroll
        for (int j = 0; j < 4; j++) o[j] = f2bf(oa[nt][j]);
        *(ushort4_t*)&attnb[((size_t)b * S_LEN + s0 + alr) * DMODEL + h * 64 + nt * 16 + alg * 4] = o;
      }
    }
  }
  grid.sync();

  // ================= Phase 3: gemm2 — 64x64 tiles; subs>=512 redo (idempotent)
  {
    unsigned short* vs = smem + sub * 16384;  // 32 KB region
    const int ASZ = 4096, BOFF = 8192, BSZ = 4096;
    int vb = blk * 3 + sub;
    int tile = vb < 512 ? vb : vb - 512;
    const int m0 = (tile >> 3) * 64, n0 = (tile & 7) * 64;
    const int wm = (wid >> 1) * 32, wn = (wid & 1) * 32;
    const unsigned short* Ab = attnb + (size_t)m0 * 512;
    const unsigned short* Bb = woutt + (size_t)n0 * 512;
    f32x4 acc[2][2] = {};

    auto stage = [&](int buf, int kt) {
#pragma unroll
      for (int c = 0; c < 2; c++) {
        int f = tl + 256 * c;
        int row = f >> 3, ch = f & 7;
        gll16(Ab + (size_t)row * 512 + kt + ((ch ^ (row & 7)) << 3),
              &vs[buf * ASZ + f * 8]);
      }
#pragma unroll
      for (int c = 0; c < 2; c++) {
        int f = tl + 256 * c;
        int row = f >> 3, ch = f & 7;
        gll16(Bb + (size_t)row * 512 + kt + ((ch ^ (row & 7)) << 3),
              &vs[BOFF + buf * BSZ + f * 8]);
      }
    };

    stage(0, 0);
    int buf = 0;
    for (int it = 0; it < 8; ++it) {
      __syncthreads();
      if (it + 1 < 8) stage(buf ^ 1, (it + 1) * 64);
      const unsigned short* Ap = &vs[buf * ASZ];
      const unsigned short* Bp = &vs[BOFF + buf * BSZ];
#pragma unroll
      for (int sl = 0; sl < 2; sl++) {
        const int cs = sl * 4 + lg;
        short8 af[2], bfv[2];
#pragma unroll
        for (int i = 0; i < 2; i++) {
          int row = wm + i * 16 + lr;
          af[i] = *(const short8*)&Ap[row * 64 + ((cs ^ (row & 7)) << 3)];
        }
#pragma unroll
        for (int i = 0; i < 2; i++) {
          int row = wn + i * 16 + lr;
          bfv[i] = *(const short8*)&Bp[row * 64 + ((cs ^ (row & 7)) << 3)];
        }
#pragma unroll
        for (int mi = 0; mi < 2; mi++)
#pragma unroll
          for (int ni = 0; ni < 2; ni++)
            acc[mi][ni] = __builtin_amdgcn_mfma_f32_16x16x32_bf16(af[mi], bfv[ni], acc[mi][ni], 0, 0, 0);
      }
      buf ^= 1;
    }

    // f32 bounce [64][64] + bias, coalesced float4 stores
    __syncthreads();
    float* ft = (float*)vs;
#pragma unroll
    for (int mi = 0; mi < 2; mi++)
#pragma unroll
      for (int ni = 0; ni < 2; ni++)
#pragma unroll
        for (int j = 0; j < 4; j++)
          ft[(wm + mi * 16 + lg * 4 + j) * 64 + wn + ni * 16 + lr] = acc[mi][ni][j];
    __syncthreads();
#pragma unroll
    for (int i = 0; i < 4; i++) {
      int s = tl + 256 * i;
      int row = s >> 4, ch = s & 15;
      float4 v = *(const float4*)&ft[row * 64 + ch * 4];
      float4 bv = *(const float4*)&bias[n0 + ch * 4];
      v.x += bv.x; v.y += bv.y; v.z += bv.z; v.w += bv.w;
      *(float4*)&out[(size_t)(m0 + row) * DMODEL + n0 + ch * 4] = v;
    }
  }
}

// ---------------- launch ----------------
extern "C" void kernel_launch(void* const* d_in, const int* in_sizes, int n_in,
                              void* d_out, int out_size, void* d_ws, size_t ws_size,
                              hipStream_t stream) {
  const float* x    = (const float*)d_in[0];
  const float* Wqkv = (const float*)d_in[1];
  const float* Wout = (const float*)d_in[2];
  const float* bout = (const float*)d_in[3];
  char* ws = (char*)d_ws;
  unsigned short* xb    = (unsigned short*)(ws + 0);
  unsigned short* wqkvt = (unsigned short*)(ws + 4194304);
  unsigned short* woutt = (unsigned short*)(ws + 5767168);
  unsigned short* Qs    = (unsigned short*)(ws + 6291456);
  unsigned short* Kp    = (unsigned short*)(ws + 10485760);
  unsigned short* Vp    = (unsigned short*)(ws + 14811136);
  unsigned short* attnb = (unsigned short*)(ws + 19922944);
  float* out = (float*)d_out;

  void* kargs[] = {(void*)&x, (void*)&Wqkv, (void*)&Wout, (void*)&bout,
                   (void*)&xb, (void*)&wqkvt, (void*)&woutt, (void*)&Qs,
                   (void*)&Kp, (void*)&Vp, (void*)&attnb, (void*)&out};
  hipLaunchCooperativeKernel(k_mega, dim3(256), dim3(768), kargs, 0, stream);
}

// Round 14
// 47.154 us; speedup vs baseline: 5.8724x; 3.0860x over previous
//
#include <hip/hip_runtime.h>
#include <hip/hip_bf16.h>
#include <stdint.h>

typedef short short8 __attribute__((ext_vector_type(8)));
typedef float f32x4 __attribute__((ext_vector_type(4)));
typedef unsigned short ushort4_t __attribute__((ext_vector_type(4)));
typedef unsigned short ushort8_t __attribute__((ext_vector_type(8)));

#define S_LEN 2048
#define NQKV 1536
#define DMODEL 512

__device__ inline unsigned short f2bf(float f) {
  unsigned int u = __float_as_uint(f);
  unsigned int r = (u + 0x7FFFu + ((u >> 16) & 1u)) >> 16;
  return (unsigned short)r;
}

// async global->LDS, 16B per lane. LDS dest must be linear in lane order.
__device__ __forceinline__ void gll16(const unsigned short* g, unsigned short* l) {
  __builtin_amdgcn_global_load_lds(
      (const __attribute__((address_space(1))) unsigned int*)g,
      (__attribute__((address_space(3))) unsigned int*)l, 16, 0, 0);
}

// ---------------- fused prep: x->bf16, weight transposes, pad zeroing --------
__global__ __launch_bounds__(256) void k_prep(const float* __restrict__ x,
                                              unsigned short* __restrict__ xb,
                                              const float* __restrict__ w1,
                                              unsigned short* __restrict__ o1,
                                              const float* __restrict__ w2,
                                              unsigned short* __restrict__ o2,
                                              unsigned short* __restrict__ Kp,
                                              unsigned short* __restrict__ Vp) {
  __shared__ float T[32][33];
  int bid = blockIdx.x;
  int t = threadIdx.x;
  if (bid < 1024) {
    int i = (bid * 256 + t) * 8;
    float4 a = *(const float4*)(x + i);
    float4 b = *(const float4*)(x + i + 4);
    ushort8_t o;
    o[0] = f2bf(a.x); o[1] = f2bf(a.y); o[2] = f2bf(a.z); o[3] = f2bf(a.w);
    o[4] = f2bf(b.x); o[5] = f2bf(b.y); o[6] = f2bf(b.z); o[7] = f2bf(b.w);
    *(ushort8_t*)(xb + i) = o;
    return;
  }
  if (bid >= 2048) {  // pad zeroing: Kp rows [0,32)+[2080,2112); Vp cols same
    int p = bid - 2048;
    ushort8_t z = {};
    if (p < 16) {
      unsigned short* dst = Kp + (size_t)p * 2112 * 64;
#pragma unroll
      for (int i = 0; i < 2; i++) {
        int s = t + 256 * i;
        int row = s >> 3, c = s & 7;
        int r2 = row < 32 ? row : row - 32 + 2080;
        *(ushort8_t*)&dst[r2 * 64 + c * 8] = z;
      }
    } else {
      unsigned short* dst = Vp + (size_t)(p - 16) * 64 * 2112;
#pragma unroll
      for (int i = 0; i < 2; i++) {
        int s = t + 256 * i;
        int d = s >> 3, side = (s >> 2) & 1, c = s & 3;
        *(ushort8_t*)&dst[(size_t)d * 2112 + side * 2080 + c * 8] = z;
      }
    }
    return;
  }
  bid -= 1024;
  int bx = bid & 63, byy = bid >> 6;
  const float* w; unsigned short* o; int cols;
  if (bx < 48) { w = w1; o = o1; cols = 1536; }
  else         { w = w2; o = o2; cols = 512; bx -= 48; }
  int r0 = byy * 32, c0 = bx * 32;
  int tr = t / 32, tc = t % 32;
#pragma unroll
  for (int i = 0; i < 4; i++) {
    int r = tr + i * 8;
    T[r][tc] = w[(size_t)(r0 + r) * cols + c0 + tc];
  }
  __syncthreads();
#pragma unroll
  for (int i = 0; i < 4; i++) {
    int rr = tr + i * 8;
    o[(size_t)(c0 + rr) * 512 + r0 + tc] = f2bf(T[tc][rr]);
  }
}

// ---------------- GEMM: C[M][N] = A[M][K](bf16) * Bt[N][K](bf16)^T ----------------
// BMxBN tile, BK=64, 4 waves (2x2). A: global_load_lds staged (both-sides XOR
// swizzle), 2-phase double buffer. B: DIRECT global->register, double-buffered
// across K-iters (b0/b1 static sets; loads issue post-barrier, consumed after
// the next barrier's vmcnt drain -> full-iteration latency cover). Removes all
// B LDS traffic (the measured binding resource in round 12).
// MODE 0: f32 out + bias via LDS bounce. MODE 1 (BN=64): Qs/Kp/Vp epilogue.
template <int BM, int BN, int MODE>
__global__ __launch_bounds__(256, 3) void k_gemm(const unsigned short* __restrict__ A,
                                                 const unsigned short* __restrict__ Bt,
                                                 void* __restrict__ Cout,
                                                 const float* __restrict__ bias,
                                                 unsigned short* __restrict__ qs,
                                                 unsigned short* __restrict__ kp,
                                                 unsigned short* __restrict__ vp,
                                                 int M, int N, int K) {
  constexpr int MR = BM / 32, NR = BN / 32;
  constexpr int CA = BM / 32;                       // A 16B chunks/thread
  constexpr int STAGE_SH = 2 * BM * 64;             // A double buffer (u16)
  constexpr int BOUNCE_SH = MODE == 0 ? BM * BN * 2 : BM * BN;
  constexpr int SMEM_SH = STAGE_SH > BOUNCE_SH ? STAGE_SH : BOUNCE_SH;
  __shared__ __align__(16) unsigned short smem[SMEM_SH];
  const int ASZ = BM * 64;

  const int t = threadIdx.x, lane = t & 63, wid = t >> 6;
  const int m0 = blockIdx.y * BM, n0 = blockIdx.x * BN;
  const int wm = (wid >> 1) * (BM / 2), wn = (wid & 1) * (BN / 2);
  const int lr = lane & 15, lg = lane >> 4;
  const unsigned short* Ab = A + (size_t)m0 * K;
  const unsigned short* Bb = Bt + (size_t)n0 * K;
  f32x4 acc[MR][NR] = {};

  const int NT = K / 64;  // even (K=512 -> 8)
  auto stage = [&](int buf, int kt) {
#pragma unroll
    for (int c = 0; c < CA; c++) {
      int f = t + 256 * c;
      int row = f >> 3, ch = f & 7;
      gll16(Ab + (size_t)row * K + kt + ((ch ^ (row & 7)) << 3),
            &smem[buf * ASZ + f * 8]);
    }
  };
  auto loadB = [&](int kt, short8 (&bv)[2][NR]) {
#pragma unroll
    for (int sl = 0; sl < 2; sl++)
#pragma unroll
      for (int i = 0; i < NR; i++) {
        int row = wn + i * 16 + lr;
        bv[sl][i] = *(const short8*)(Bb + (size_t)row * K + kt + (sl * 4 + lg) * 8);
      }
  };
  auto compute = [&](int buf, short8 (&bv)[2][NR]) {
    const unsigned short* Ap = &smem[buf * ASZ];
#pragma unroll
    for (int sl = 0; sl < 2; sl++) {
      const int cs = sl * 4 + lg;
      short8 af[MR];
#pragma unroll
      for (int i = 0; i < MR; i++) {
        int row = wm + i * 16 + lr;
        af[i] = *(const short8*)&Ap[row * 64 + ((cs ^ (row & 7)) << 3)];
      }
#pragma unroll
      for (int mi = 0; mi < MR; mi++)
#pragma unroll
        for (int ni = 0; ni < NR; ni++)
          acc[mi][ni] = __builtin_amdgcn_mfma_f32_16x16x32_bf16(af[mi], bv[sl][ni], acc[mi][ni], 0, 0, 0);
    }
  };

  short8 b0[2][NR], b1[2][NR];
  stage(0, 0);
  loadB(0, b0);
  for (int it = 0; it < NT; it += 2) {
    __syncthreads();                       // A tile it + B set for it landed
    if (it + 1 < NT) { stage(1, (it + 1) * 64); loadB((it + 1) * 64, b1); }
    compute(0, b0);
    __syncthreads();                       // all waves done reading buf0
    if (it + 2 < NT) { stage(0, (it + 2) * 64); loadB((it + 2) * 64, b0); }
    compute(1, b1);
  }

  if (MODE == 0) {
    // ---- f32 bounce: [BM][BN] f32, coalesced float4 stores + bias ----
    __syncthreads();
    float* ft = (float*)smem;
#pragma unroll
    for (int mi = 0; mi < MR; mi++)
#pragma unroll
      for (int ni = 0; ni < NR; ni++)
#pragma unroll
        for (int j = 0; j < 4; j++)
          ft[(wm + mi * 16 + lg * 4 + j) * BN + wn + ni * 16 + lr] = acc[mi][ni][j];
    __syncthreads();
#pragma unroll
    for (int i = 0; i < BM * BN / 1024; i++) {
      int s = t + 256 * i;
      int row = s / (BN / 4), ch = s % (BN / 4);
      float4 v = *(const float4*)&ft[row * BN + ch * 4];
      float4 bv = *(const float4*)&bias[n0 + ch * 4];
      v.x += bv.x; v.y += bv.y; v.z += bv.z; v.w += bv.w;
      *(float4*)&((float*)Cout)[(size_t)(m0 + row) * N + n0 + ch * 4] = v;
    }
  } else {
    // ---- swizzled bf16 bounce [BM][64] + de-interleaved contiguous stores ----
    __syncthreads();
#pragma unroll
    for (int mi = 0; mi < MR; mi++)
#pragma unroll
      for (int ni = 0; ni < NR; ni++)
#pragma unroll
        for (int j = 0; j < 4; j++) {
          int row = wm + mi * 16 + lg * 4 + j;
          int col = wn + ni * 16 + lr;
          smem[row * 64 + (((col >> 3) ^ ((row >> 3) & 7)) << 3) + (col & 7)] =
              f2bf(acc[mi][ni][j]);
        }
    __syncthreads();

    const int b_ = m0 >> 11;
    const int posb = m0 & 2047;
    const int h = n0 / 192, seg = (n0 % 192) >> 6;
    if (seg < 2) {
      unsigned short* dst = (seg == 0)
          ? qs + ((size_t)(b_ * 8 + h) * 2048 + posb) * 64
          : kp + ((size_t)(b_ * 8 + h) * 2112 + 32 + posb) * 64;
#pragma unroll
      for (int i = 0; i < BM / 32; i++) {
        int s = t + 256 * i;
        int row = s >> 3, ch = s & 7;
        int src = row * 64 + ((ch ^ ((row >> 3) & 7)) << 3);
        *(ushort8_t*)&dst[s * 8] = *(const ushort8_t*)&smem[src];
      }
    } else {
      unsigned short* dst = vp + (size_t)(b_ * 8 + h) * 64 * 2112;
#pragma unroll
      for (int i = 0; i < BM / 32; i++) {
        int s = t + 256 * i;
        int dl = s / (BM / 8), pc = s % (BM / 8);
        ushort8_t v;
#pragma unroll
        for (int j = 0; j < 8; j++) {
          int row = pc * 8 + j;
          v[j] = smem[row * 64 + ((((dl >> 3) ^ (pc & 7)) << 3)) + (dl & 7)];
        }
        *(ushort8_t*)&dst[(size_t)dl * 2112 + 32 + posb + pc * 8] = v;
      }
    }
  }
}

// ---------------- windowed attention: 128-q blocks, 8 waves ------------------
// K/V LDS-staged (swizzled); Q read DIRECT from global (single-use, L2-hot),
// loads issued before staging so latency overlaps.
__global__ __launch_bounds__(512) void k_attn(const unsigned short* __restrict__ Qs,
                                              const unsigned short* __restrict__ Kp,
                                              const unsigned short* __restrict__ Vp,
                                              unsigned short* __restrict__ attnb) {
  __shared__ __align__(16) unsigned short Kt[192 * 64];  // pos-local x d, swz (24 KB)
  __shared__ __align__(16) unsigned short Vt[64 * 256];  // d x pos-local, swz (32 KB)
  const int t = threadIdx.x, lane = t & 63, w = t >> 6;   // w 0..7
  const int blk = blockIdx.x;
  const int sbi = blk & 15, h = (blk >> 4) & 7, b = blk >> 7;
  const int sb = sbi * 128;
  const int bh = b * 8 + h;
  const int lr = lane & 15, lg = lane >> 4;

  // Q fragments direct from global (B-operand of swapped QK^T)
  short8 qb[2];
#pragma unroll
  for (int ks = 0; ks < 2; ks++)
    qb[ks] = *(const short8*)(Qs + ((size_t)bh * 2048 + sb + w * 16 + lr) * 64 + ks * 32 + lg * 8);

  {  // stage K: Kp idx sb..sb+191 (= global pos sb-32..sb+159)
    const unsigned short* src = Kp + ((size_t)bh * 2112 + sb) * 64;
#pragma unroll
    for (int i = 0; i < 3; i++) {
      int s = t + 512 * i, row = s >> 3, c = s & 7;
      gll16(src + row * 64 + (c ^ (row & 7)) * 8, &Kt[s * 8]);
    }
  }
  {  // stage V: Vp cols sb..sb+255 (= global pos sb-32..sb+223)
    const unsigned short* src = Vp + (size_t)bh * 64 * 2112 + sb;
#pragma unroll
    for (int i = 0; i < 4; i++) {
      int s = t + 512 * i, d = s >> 5, c = s & 31;
      gll16(src + (size_t)d * 2112 + (c ^ (d & 7)) * 8, &Vt[s * 8]);
    }
  }
  __syncthreads();

  const int sw = (lr & 7) << 3;  // u16 read-XOR (16B chunks)

  // S^T: col = q = lr, row = pos_local(rel s0-32) = ct*16 + lg*4 + j
  f32x4 sc[5] = {};
#pragma unroll
  for (int ct = 0; ct < 5; ct++) {
#pragma unroll
    for (int ks = 0; ks < 2; ks++) {
      short8 ka = *(const short8*)&Kt[(w * 16 + ct * 16 + lr) * 64 + ((ks * 32 + lg * 8) ^ sw)];
      sc[ct] = __builtin_amdgcn_mfma_f32_16x16x32_bf16(ka, qb[ks], sc[ct], 0, 0, 0);
    }
  }

  float mx = -1e30f;
#pragma unroll
  for (int ct = 0; ct < 5; ct++)
#pragma unroll
    for (int j = 0; j < 4; j++) {
      int c2 = ct * 16 + lg * 4 + j;
      sc[ct][j] = (c2 >= lr && c2 <= lr + 64) ? sc[ct][j] * 0.125f : -1e30f;
      mx = fmaxf(mx, sc[ct][j]);
    }
  mx = fmaxf(mx, __shfl_xor(mx, 16, 64));
  mx = fmaxf(mx, __shfl_xor(mx, 32, 64));

  float pn[5][4];
  float sum = 0.0f;
#pragma unroll
  for (int ct = 0; ct < 5; ct++)
#pragma unroll
    for (int j = 0; j < 4; j++) {
      pn[ct][j] = __expf(sc[ct][j] - mx);
      sum += pn[ct][j];
    }
  sum += __shfl_xor(sum, 16, 64);
  sum += __shfl_xor(sum, 32, 64);
  float inv = 1.0f / sum;

  unsigned int w01[5], w23[5];
#pragma unroll
  for (int ct = 0; ct < 5; ct++) {
    w01[ct] = (unsigned int)f2bf(pn[ct][0] * inv) | ((unsigned int)f2bf(pn[ct][1] * inv) << 16);
    w23[ct] = (unsigned int)f2bf(pn[ct][2] * inv) | ((unsigned int)f2bf(pn[ct][3] * inv) << 16);
  }

  f32x4 oa[4] = {};
  const int h2 = lg & 1, tl = lg >> 1;
  const int sA = 32 * h2 + lr, sB = sA + 16;
#pragma unroll
  for (int ks = 0; ks < 3; ks++) {
    const int T0 = 2 * ks;
    const int T1 = (2 * ks + 1 < 5) ? (2 * ks + 1) : 4;
    unsigned int a0 = __shfl((int)w01[T0], sA, 64), a1 = __shfl((int)w23[T0], sA, 64);
    unsigned int a2 = __shfl((int)w01[T0], sB, 64), a3 = __shfl((int)w23[T0], sB, 64);
    unsigned int b0 = __shfl((int)w01[T1], sA, 64), b1 = __shfl((int)w23[T1], sA, 64);
    unsigned int b2 = __shfl((int)w01[T1], sB, 64), b3 = __shfl((int)w23[T1], sB, 64);
    union { unsigned int u[4]; short8 v; } pb;
    pb.u[0] = tl ? b0 : a0;
    pb.u[1] = tl ? b1 : a1;
    pb.u[2] = tl ? b2 : a2;
    pb.u[3] = tl ? b3 : a3;
    if (ks == 2 && tl) { pb.u[0] = 0; pb.u[1] = 0; pb.u[2] = 0; pb.u[3] = 0; }
    int pofl = w * 16 + ks * 32 + lg * 8;
#pragma unroll
    for (int nt = 0; nt < 4; nt++) {
      short8 va = *(const short8*)&Vt[(nt * 16 + lr) * 256 + (pofl ^ sw)];
      oa[nt] = __builtin_amdgcn_mfma_f32_16x16x32_bf16(va, pb.v, oa[nt], 0, 0, 0);
    }
  }

  const int s0 = sb + w * 16;
#pragma unroll
  for (int nt = 0; nt < 4; nt++) {
    ushort4_t o;
#pragma unroll
    for (int j = 0; j < 4; j++) o[j] = f2bf(oa[nt][j]);
    *(ushort4_t*)&attnb[((size_t)b * S_LEN + s0 + lr) * DMODEL + h * 64 + nt * 16 + lg * 4] = o;
  }
}

// ---------------- launch ----------------
extern "C" void kernel_launch(void* const* d_in, const int* in_sizes, int n_in,
                              void* d_out, int out_size, void* d_ws, size_t ws_size,
                              hipStream_t stream) {
  const float* x    = (const float*)d_in[0];
  const float* Wqkv = (const float*)d_in[1];
  const float* Wout = (const float*)d_in[2];
  const float* bout = (const float*)d_in[3];
  char* ws = (char*)d_ws;
  unsigned short* xb    = (unsigned short*)(ws + 0);         // 4096x512 bf16 (4 MB)
  unsigned short* wqkvt = (unsigned short*)(ws + 4194304);   // 1536x512 bf16 (1.5 MB)
  unsigned short* woutt = (unsigned short*)(ws + 5767168);   // 512x512 bf16  (0.5 MB)
  unsigned short* Qs    = (unsigned short*)(ws + 6291456);   // [16][2048][64] (4 MB)
  unsigned short* Kp    = (unsigned short*)(ws + 10485760);  // [16][2112][64] (4.125 MB)
  unsigned short* Vp    = (unsigned short*)(ws + 14811136);  // [16][64][2112] (4.125 MB + slack)
  unsigned short* attnb = (unsigned short*)(ws + 19922944);  // 4096x512 bf16 (4 MB)

  hipLaunchKernelGGL(k_prep, dim3(2080), dim3(256), 0, stream,
                     x, xb, Wqkv, wqkvt, Wout, woutt, Kp, Vp);
  hipLaunchKernelGGL((k_gemm<128, 64, 1>), dim3(24, 32), dim3(256), 0, stream,
                     xb, wqkvt, nullptr, (const float*)nullptr, Qs, Kp, Vp, 4096, 1536, 512);
  hipLaunchKernelGGL(k_attn, dim3(256), dim3(512), 0, stream, Qs, Kp, Vp, attnb);
  hipLaunchKernelGGL((k_gemm<64, 64, 0>), dim3(8, 64), dim3(256), 0, stream,
                     attnb, woutt, d_out, bout,
                     (unsigned short*)nullptr, (unsigned short*)nullptr,
                     (unsigned short*)nullptr, 4096, 512, 512);
}

// Round 15
// 37.349 us; speedup vs baseline: 7.4141x; 1.2625x over previous
//
#include <hip/hip_runtime.h>
#include <hip/hip_bf16.h>
#include <stdint.h>

typedef short short8 __attribute__((ext_vector_type(8)));
typedef float f32x4 __attribute__((ext_vector_type(4)));
typedef unsigned short ushort4_t __attribute__((ext_vector_type(4)));
typedef unsigned short ushort8_t __attribute__((ext_vector_type(8)));

#define S_LEN 2048
#define NQKV 1536
#define DMODEL 512

__device__ inline unsigned short f2bf(float f) {
  unsigned int u = __float_as_uint(f);
  unsigned int r = (u + 0x7FFFu + ((u >> 16) & 1u)) >> 16;
  return (unsigned short)r;
}

// async global->LDS, 16B per lane. LDS dest must be linear in lane order.
__device__ __forceinline__ void gll16(const unsigned short* g, unsigned short* l) {
  __builtin_amdgcn_global_load_lds(
      (const __attribute__((address_space(1))) unsigned int*)g,
      (__attribute__((address_space(3))) unsigned int*)l, 16, 0, 0);
}

// ---------------- fused prep: x->bf16, weight transposes, pad zeroing --------
__global__ __launch_bounds__(256) void k_prep(const float* __restrict__ x,
                                              unsigned short* __restrict__ xb,
                                              const float* __restrict__ w1,
                                              unsigned short* __restrict__ o1,
                                              const float* __restrict__ w2,
                                              unsigned short* __restrict__ o2,
                                              unsigned short* __restrict__ Kp,
                                              unsigned short* __restrict__ Vp) {
  __shared__ float T[32][33];
  int bid = blockIdx.x;
  int t = threadIdx.x;
  if (bid < 1024) {
    int i = (bid * 256 + t) * 8;
    float4 a = *(const float4*)(x + i);
    float4 b = *(const float4*)(x + i + 4);
    ushort8_t o;
    o[0] = f2bf(a.x); o[1] = f2bf(a.y); o[2] = f2bf(a.z); o[3] = f2bf(a.w);
    o[4] = f2bf(b.x); o[5] = f2bf(b.y); o[6] = f2bf(b.z); o[7] = f2bf(b.w);
    *(ushort8_t*)(xb + i) = o;
    return;
  }
  if (bid >= 2048) {  // pad zeroing: Kp rows [0,32)+[2080,2112); Vp cols same
    int p = bid - 2048;
    ushort8_t z = {};
    if (p < 16) {
      unsigned short* dst = Kp + (size_t)p * 2112 * 64;
#pragma unroll
      for (int i = 0; i < 2; i++) {
        int s = t + 256 * i;
        int row = s >> 3, c = s & 7;
        int r2 = row < 32 ? row : row - 32 + 2080;
        *(ushort8_t*)&dst[r2 * 64 + c * 8] = z;
      }
    } else {
      unsigned short* dst = Vp + (size_t)(p - 16) * 64 * 2112;
#pragma unroll
      for (int i = 0; i < 2; i++) {
        int s = t + 256 * i;
        int d = s >> 3, side = (s >> 2) & 1, c = s & 3;
        *(ushort8_t*)&dst[(size_t)d * 2112 + side * 2080 + c * 8] = z;
      }
    }
    return;
  }
  bid -= 1024;
  int bx = bid & 63, byy = bid >> 6;
  const float* w; unsigned short* o; int cols;
  if (bx < 48) { w = w1; o = o1; cols = 1536; }
  else         { w = w2; o = o2; cols = 512; bx -= 48; }
  int r0 = byy * 32, c0 = bx * 32;
  int tr = t / 32, tc = t % 32;
#pragma unroll
  for (int i = 0; i < 4; i++) {
    int r = tr + i * 8;
    T[r][tc] = w[(size_t)(r0 + r) * cols + c0 + tc];
  }
  __syncthreads();
#pragma unroll
  for (int i = 0; i < 4; i++) {
    int rr = tr + i * 8;
    o[(size_t)(c0 + rr) * 512 + r0 + tc] = f2bf(T[tc][rr]);
  }
}

// ---------------- GEMM: C[M][N] = A[M][K](bf16) * Bt[N][K](bf16)^T ----------------
// BMxBN tile, BK=64, 4 waves, global_load_lds staging (both-sides XOR swizzle),
// 2-phase double buffer. K-loop identical to round 11.
// MODE 0 (BN=64): f32 out + bias via LDS bounce, coalesced float4 stores.
// MODE 1 (BN=128): wave tile 64x64 (2.0 MFMA per ds_read); [128][128] swizzled
//                  bounce + hf-loop epilogue to Qs / Kp(+32 pad) / Vp (transposed).
template <int BM, int BN, int MODE>
__global__ __launch_bounds__(256) void k_gemm(const unsigned short* __restrict__ A,
                                              const unsigned short* __restrict__ Bt,
                                              void* __restrict__ Cout,
                                              const float* __restrict__ bias,
                                              unsigned short* __restrict__ qs,
                                              unsigned short* __restrict__ kp,
                                              unsigned short* __restrict__ vp,
                                              int M, int N, int K) {
  constexpr int MR = BM / 32, NR = BN / 32;
  constexpr int CA = BM / 32, CB = BN / 32;        // 16B chunks/thread at BK=64
  constexpr int STAGE_SH = 2 * (BM + BN) * 64;
  constexpr int BOUNCE_SH = MODE == 0 ? BM * BN * 2 : BM * 128;
  constexpr int SMEM_SH = STAGE_SH > BOUNCE_SH ? STAGE_SH : BOUNCE_SH;
  __shared__ __align__(16) unsigned short smem[SMEM_SH];
  const int ASZ = BM * 64, BOFF = 2 * BM * 64, BSZ = BN * 64;

  const int t = threadIdx.x, lane = t & 63, wid = t >> 6;
  const int m0 = blockIdx.y * BM, n0 = blockIdx.x * BN;
  const int wm = (wid >> 1) * (BM / 2), wn = (wid & 1) * (BN / 2);
  const int lr = lane & 15, lg = lane >> 4;
  const unsigned short* Ab = A + (size_t)m0 * K;
  const unsigned short* Bb = Bt + (size_t)n0 * K;
  f32x4 acc[MR][NR] = {};

  const int NT = K / 64;
  auto stage = [&](int buf, int kt) {
#pragma unroll
    for (int c = 0; c < CA; c++) {
      int f = t + 256 * c;
      int row = f >> 3, ch = f & 7;
      gll16(Ab + (size_t)row * K + kt + ((ch ^ (row & 7)) << 3),
            &smem[buf * ASZ + f * 8]);
    }
#pragma unroll
    for (int c = 0; c < CB; c++) {
      int f = t + 256 * c;
      int row = f >> 3, ch = f & 7;
      gll16(Bb + (size_t)row * K + kt + ((ch ^ (row & 7)) << 3),
            &smem[BOFF + buf * BSZ + f * 8]);
    }
  };

  stage(0, 0);
  int buf = 0;
  for (int it = 0; it < NT; ++it) {
    __syncthreads();
    if (it + 1 < NT) stage(buf ^ 1, (it + 1) * 64);
    const unsigned short* Ap = &smem[buf * ASZ];
    const unsigned short* Bp = &smem[BOFF + buf * BSZ];
#pragma unroll
    for (int sl = 0; sl < 2; sl++) {
      const int cs = sl * 4 + lg;                  // 16B chunk within the row
      short8 af[MR], bfv[NR];
#pragma unroll
      for (int i = 0; i < MR; i++) {
        int row = wm + i * 16 + lr;
        af[i] = *(const short8*)&Ap[row * 64 + ((cs ^ (row & 7)) << 3)];
      }
#pragma unroll
      for (int i = 0; i < NR; i++) {
        int row = wn + i * 16 + lr;
        bfv[i] = *(const short8*)&Bp[row * 64 + ((cs ^ (row & 7)) << 3)];
      }
#pragma unroll
      for (int mi = 0; mi < MR; mi++)
#pragma unroll
        for (int ni = 0; ni < NR; ni++)
          acc[mi][ni] = __builtin_amdgcn_mfma_f32_16x16x32_bf16(af[mi], bfv[ni], acc[mi][ni], 0, 0, 0);
    }
    buf ^= 1;
  }

  if (MODE == 0) {
    // ---- f32 bounce: [BM][BN] f32, coalesced float4 stores + bias ----
    __syncthreads();
    float* ft = (float*)smem;
#pragma unroll
    for (int mi = 0; mi < MR; mi++)
#pragma unroll
      for (int ni = 0; ni < NR; ni++)
#pragma unroll
        for (int j = 0; j < 4; j++)
          ft[(wm + mi * 16 + lg * 4 + j) * BN + wn + ni * 16 + lr] = acc[mi][ni][j];
    __syncthreads();
#pragma unroll
    for (int i = 0; i < BM * BN / 1024; i++) {
      int s = t + 256 * i;
      int row = s / (BN / 4), ch = s % (BN / 4);
      float4 v = *(const float4*)&ft[row * BN + ch * 4];
      float4 bv = *(const float4*)&bias[n0 + ch * 4];
      v.x += bv.x; v.y += bv.y; v.z += bv.z; v.w += bv.w;
      *(float4*)&((float*)Cout)[(size_t)(m0 + row) * N + n0 + ch * 4] = v;
    }
  } else {
    // ---- swizzled bf16 bounce [128][128]; u16 idx = row*128 + (col ^ (((row>>3)&7)<<3))
    __syncthreads();
#pragma unroll
    for (int mi = 0; mi < MR; mi++)
#pragma unroll
      for (int ni = 0; ni < NR; ni++)
#pragma unroll
        for (int j = 0; j < 4; j++) {
          int row = wm + mi * 16 + lg * 4 + j;
          int col = wn + ni * 16 + lr;
          smem[row * 128 + (col ^ (((row >> 3) & 7) << 3))] = f2bf(acc[mi][ni][j]);
        }
    __syncthreads();

    const int b_ = m0 >> 11;
    const int posb = m0 & 2047;
#pragma unroll
    for (int hf = 0; hf < 2; hf++) {
      int c_abs = n0 + hf * 64;
      int h = c_abs / 192, seg = (c_abs % 192) >> 6;  // 0=q, 1=k, 2=v
      if (seg < 2) {
        unsigned short* dst = (seg == 0)
            ? qs + ((size_t)(b_ * 8 + h) * 2048 + posb) * 64
            : kp + ((size_t)(b_ * 8 + h) * 2112 + 32 + posb) * 64;
#pragma unroll
        for (int i = 0; i < 4; i++) {
          int s = t + 256 * i;            // 1024 chunks: 128 rows x 8
          int row = s >> 3, ch = s & 7;
          int src = row * 128 + ((hf * 64 + ch * 8) ^ (((row >> 3) & 7) << 3));
          *(ushort8_t*)&dst[s * 8] = *(const ushort8_t*)&smem[src];
        }
      } else {
        unsigned short* dst = vp + (size_t)(b_ * 8 + h) * 64 * 2112;
#pragma unroll
        for (int i = 0; i < 4; i++) {
          int s = t + 256 * i;            // dl 0..63, pc 0..15
          int dl = s >> 4, pc = s & 15;
          ushort8_t v;
#pragma unroll
          for (int j = 0; j < 8; j++) {
            int row = pc * 8 + j;
            v[j] = smem[row * 128 + ((hf * 64 + dl) ^ (((row >> 3) & 7) << 3))];
          }
          *(ushort8_t*)&dst[(size_t)dl * 2112 + 32 + posb + pc * 8] = v;
        }
      }
    }
  }
}

// ---------------- windowed attention: 128-q blocks, 8 waves, LDS-staged ------
__global__ __launch_bounds__(512) void k_attn(const unsigned short* __restrict__ Qs,
                                              const unsigned short* __restrict__ Kp,
                                              const unsigned short* __restrict__ Vp,
                                              unsigned short* __restrict__ attnb) {
  __shared__ __align__(16) unsigned short Kt[192 * 64];  // pos-local x d, swz (24 KB)
  __shared__ __align__(16) unsigned short Vt[64 * 256];  // d x pos-local, swz (32 KB)
  __shared__ __align__(16) unsigned short Qt[128 * 64];  // q-local x d, swz  (16 KB)
  const int t = threadIdx.x, lane = t & 63, w = t >> 6;   // w 0..7
  const int blk = blockIdx.x;
  const int sbi = blk & 15, h = (blk >> 4) & 7, b = blk >> 7;
  const int sb = sbi * 128;
  const int bh = b * 8 + h;
  const int lr = lane & 15, lg = lane >> 4;

  {  // stage K: Kp idx sb..sb+191 (= global pos sb-32..sb+159)
    const unsigned short* src = Kp + ((size_t)bh * 2112 + sb) * 64;
#pragma unroll
    for (int i = 0; i < 3; i++) {
      int s = t + 512 * i, row = s >> 3, c = s & 7;
      gll16(src + row * 64 + (c ^ (row & 7)) * 8, &Kt[s * 8]);
    }
  }
  {  // stage V: Vp cols sb..sb+255 (= global pos sb-32..sb+223)
    const unsigned short* src = Vp + (size_t)bh * 64 * 2112 + sb;
#pragma unroll
    for (int i = 0; i < 4; i++) {
      int s = t + 512 * i, d = s >> 5, c = s & 31;
      gll16(src + (size_t)d * 2112 + (c ^ (d & 7)) * 8, &Vt[s * 8]);
    }
  }
  {  // stage Q: rows sb..sb+127
    const unsigned short* src = Qs + ((size_t)bh * 2048 + sb) * 64;
#pragma unroll
    for (int i = 0; i < 2; i++) {
      int s = t + 512 * i, row = s >> 3, c = s & 7;
      gll16(src + row * 64 + (c ^ (row & 7)) * 8, &Qt[s * 8]);
    }
  }
  __syncthreads();

  const int sw = (lr & 7) << 3;  // u16 read-XOR (16B chunks)

  short8 qb[2];
#pragma unroll
  for (int ks = 0; ks < 2; ks++)
    qb[ks] = *(const short8*)&Qt[(w * 16 + lr) * 64 + ((ks * 32 + lg * 8) ^ sw)];

  // S^T: col = q = lr, row = pos_local(rel s0-32) = ct*16 + lg*4 + j
  f32x4 sc[5] = {};
#pragma unroll
  for (int ct = 0; ct < 5; ct++) {
#pragma unroll
    for (int ks = 0; ks < 2; ks++) {
      short8 ka = *(const short8*)&Kt[(w * 16 + ct * 16 + lr) * 64 + ((ks * 32 + lg * 8) ^ sw)];
      sc[ct] = __builtin_amdgcn_mfma_f32_16x16x32_bf16(ka, qb[ks], sc[ct], 0, 0, 0);
    }
  }

  float mx = -1e30f;
#pragma unroll
  for (int ct = 0; ct < 5; ct++)
#pragma unroll
    for (int j = 0; j < 4; j++) {
      int c2 = ct * 16 + lg * 4 + j;
      sc[ct][j] = (c2 >= lr && c2 <= lr + 64) ? sc[ct][j] * 0.125f : -1e30f;
      mx = fmaxf(mx, sc[ct][j]);
    }
  mx = fmaxf(mx, __shfl_xor(mx, 16, 64));
  mx = fmaxf(mx, __shfl_xor(mx, 32, 64));

  float pn[5][4];
  float sum = 0.0f;
#pragma unroll
  for (int ct = 0; ct < 5; ct++)
#pragma unroll
    for (int j = 0; j < 4; j++) {
      pn[ct][j] = __expf(sc[ct][j] - mx);
      sum += pn[ct][j];
    }
  sum += __shfl_xor(sum, 16, 64);
  sum += __shfl_xor(sum, 32, 64);
  float inv = 1.0f / sum;

  unsigned int w01[5], w23[5];
#pragma unroll
  for (int ct = 0; ct < 5; ct++) {
    w01[ct] = (unsigned int)f2bf(pn[ct][0] * inv) | ((unsigned int)f2bf(pn[ct][1] * inv) << 16);
    w23[ct] = (unsigned int)f2bf(pn[ct][2] * inv) | ((unsigned int)f2bf(pn[ct][3] * inv) << 16);
  }

  f32x4 oa[4] = {};
  const int h2 = lg & 1, tl = lg >> 1;
  const int sA = 32 * h2 + lr, sB = sA + 16;
#pragma unroll
  for (int ks = 0; ks < 3; ks++) {
    const int T0 = 2 * ks;
    const int T1 = (2 * ks + 1 < 5) ? (2 * ks + 1) : 4;
    unsigned int a0 = __shfl((int)w01[T0], sA, 64), a1 = __shfl((int)w23[T0], sA, 64);
    unsigned int a2 = __shfl((int)w01[T0], sB, 64), a3 = __shfl((int)w23[T0], sB, 64);
    unsigned int b0 = __shfl((int)w01[T1], sA, 64), b1 = __shfl((int)w23[T1], sA, 64);
    unsigned int b2 = __shfl((int)w01[T1], sB, 64), b3 = __shfl((int)w23[T1], sB, 64);
    union { unsigned int u[4]; short8 v; } pb;
    pb.u[0] = tl ? b0 : a0;
    pb.u[1] = tl ? b1 : a1;
    pb.u[2] = tl ? b2 : a2;
    pb.u[3] = tl ? b3 : a3;
    if (ks == 2 && tl) { pb.u[0] = 0; pb.u[1] = 0; pb.u[2] = 0; pb.u[3] = 0; }
    int pofl = w * 16 + ks * 32 + lg * 8;
#pragma unroll
    for (int nt = 0; nt < 4; nt++) {
      short8 va = *(const short8*)&Vt[(nt * 16 + lr) * 256 + (pofl ^ sw)];
      oa[nt] = __builtin_amdgcn_mfma_f32_16x16x32_bf16(va, pb.v, oa[nt], 0, 0, 0);
    }
  }

  const int s0 = sb + w * 16;
#pragma unroll
  for (int nt = 0; nt < 4; nt++) {
    ushort4_t o;
#pragma unroll
    for (int j = 0; j < 4; j++) o[j] = f2bf(oa[nt][j]);
    *(ushort4_t*)&attnb[((size_t)b * S_LEN + s0 + lr) * DMODEL + h * 64 + nt * 16 + lg * 4] = o;
  }
}

// ---------------- launch ----------------
extern "C" void kernel_launch(void* const* d_in, const int* in_sizes, int n_in,
                              void* d_out, int out_size, void* d_ws, size_t ws_size,
                              hipStream_t stream) {
  const float* x    = (const float*)d_in[0];
  const float* Wqkv = (const float*)d_in[1];
  const float* Wout = (const float*)d_in[2];
  const float* bout = (const float*)d_in[3];
  char* ws = (char*)d_ws;
  unsigned short* xb    = (unsigned short*)(ws + 0);         // 4096x512 bf16 (4 MB)
  unsigned short* wqkvt = (unsigned short*)(ws + 4194304);   // 1536x512 bf16 (1.5 MB)
  unsigned short* woutt = (unsigned short*)(ws + 5767168);   // 512x512 bf16  (0.5 MB)
  unsigned short* Qs    = (unsigned short*)(ws + 6291456);   // [16][2048][64] (4 MB)
  unsigned short* Kp    = (unsigned short*)(ws + 10485760);  // [16][2112][64] (4.125 MB)
  unsigned short* Vp    = (unsigned short*)(ws + 14811136);  // [16][64][2112] (4.125 MB + slack)
  unsigned short* attnb = (unsigned short*)(ws + 19922944);  // 4096x512 bf16 (4 MB)

  hipLaunchKernelGGL(k_prep, dim3(2080), dim3(256), 0, stream,
                     x, xb, Wqkv, wqkvt, Wout, woutt, Kp, Vp);
  hipLaunchKernelGGL((k_gemm<128, 128, 1>), dim3(12, 32), dim3(256), 0, stream,
                     xb, wqkvt, nullptr, (const float*)nullptr, Qs, Kp, Vp, 4096, 1536, 512);
  hipLaunchKernelGGL(k_attn, dim3(256), dim3(512), 0, stream, Qs, Kp, Vp, attnb);
  hipLaunchKernelGGL((k_gemm<64, 64, 0>), dim3(8, 64), dim3(256), 0, stream,
                     attnb, woutt, d_out, bout,
                     (unsigned short*)nullptr, (unsigned short*)nullptr,
                     (unsigned short*)nullptr, 4096, 512, 512);
}

// Round 16
// 36.534 us; speedup vs baseline: 7.5794x; 1.0223x over previous
//
#include <hip/hip_runtime.h>
#include <hip/hip_bf16.h>
#include <stdint.h>

typedef short short8 __attribute__((ext_vector_type(8)));
typedef float f32x4 __attribute__((ext_vector_type(4)));
typedef unsigned short ushort4_t __attribute__((ext_vector_type(4)));
typedef unsigned short ushort8_t __attribute__((ext_vector_type(8)));

#define S_LEN 2048
#define NQKV 1536
#define DMODEL 512

__device__ inline unsigned short f2bf(float f) {
  unsigned int u = __float_as_uint(f);
  unsigned int r = (u + 0x7FFFu + ((u >> 16) & 1u)) >> 16;
  return (unsigned short)r;
}

// async global->LDS, 16B per lane. LDS dest must be linear in lane order.
__device__ __forceinline__ void gll16(const unsigned short* g, unsigned short* l) {
  __builtin_amdgcn_global_load_lds(
      (const __attribute__((address_space(1))) unsigned int*)g,
      (__attribute__((address_space(3))) unsigned int*)l, 16, 0, 0);
}

// ---------------- fused prep: x->bf16, weight transposes, pad zeroing --------
__global__ __launch_bounds__(256) void k_prep(const float* __restrict__ x,
                                              unsigned short* __restrict__ xb,
                                              const float* __restrict__ w1,
                                              unsigned short* __restrict__ o1,
                                              const float* __restrict__ w2,
                                              unsigned short* __restrict__ o2,
                                              unsigned short* __restrict__ Kp,
                                              unsigned short* __restrict__ Vp) {
  __shared__ float T[32][33];
  int bid = blockIdx.x;
  int t = threadIdx.x;
  if (bid < 1024) {
    int i = (bid * 256 + t) * 8;
    float4 a = *(const float4*)(x + i);
    float4 b = *(const float4*)(x + i + 4);
    ushort8_t o;
    o[0] = f2bf(a.x); o[1] = f2bf(a.y); o[2] = f2bf(a.z); o[3] = f2bf(a.w);
    o[4] = f2bf(b.x); o[5] = f2bf(b.y); o[6] = f2bf(b.z); o[7] = f2bf(b.w);
    *(ushort8_t*)(xb + i) = o;
    return;
  }
  if (bid >= 2048) {  // pad zeroing: Kp rows [0,32)+[2080,2112); Vp cols same
    int p = bid - 2048;
    ushort8_t z = {};
    if (p < 16) {
      unsigned short* dst = Kp + (size_t)p * 2112 * 64;
#pragma unroll
      for (int i = 0; i < 2; i++) {
        int s = t + 256 * i;
        int row = s >> 3, c = s & 7;
        int r2 = row < 32 ? row : row - 32 + 2080;
        *(ushort8_t*)&dst[r2 * 64 + c * 8] = z;
      }
    } else {
      unsigned short* dst = Vp + (size_t)(p - 16) * 64 * 2112;
#pragma unroll
      for (int i = 0; i < 2; i++) {
        int s = t + 256 * i;
        int d = s >> 3, side = (s >> 2) & 1, c = s & 3;
        *(ushort8_t*)&dst[(size_t)d * 2112 + side * 2080 + c * 8] = z;
      }
    }
    return;
  }
  bid -= 1024;
  int bx = bid & 63, byy = bid >> 6;
  const float* w; unsigned short* o; int cols;
  if (bx < 48) { w = w1; o = o1; cols = 1536; }
  else         { w = w2; o = o2; cols = 512; bx -= 48; }
  int r0 = byy * 32, c0 = bx * 32;
  int tr = t / 32, tc = t % 32;
#pragma unroll
  for (int i = 0; i < 4; i++) {
    int r = tr + i * 8;
    T[r][tc] = w[(size_t)(r0 + r) * cols + c0 + tc];
  }
  __syncthreads();
#pragma unroll
  for (int i = 0; i < 4; i++) {
    int rr = tr + i * 8;
    o[(size_t)(c0 + rr) * 512 + r0 + tc] = f2bf(T[tc][rr]);
  }
}

// ---------------- GEMM: C[M][N] = A[M][K](bf16) * Bt[N][K](bf16)^T ----------------
// BMxBN tile, BK=64, 4 waves (2x2), global_load_lds staging (both-sides XOR
// swizzle: pre-swizzled global source chunk + same XOR on ds_read -> 2-way),
// 2-phase double buffer.
// MODE 0: f32 out + bias via LDS bounce, coalesced float4 stores.
// MODE 1 (BN=64): block's 64 cols are one pure q/k/v segment; swizzled bounce,
//                 contiguous 16B stores (Qs / Kp shifted / Vp transposed).
template <int BM, int BN, int MODE>
__global__ __launch_bounds__(256) void k_gemm(const unsigned short* __restrict__ A,
                                              const unsigned short* __restrict__ Bt,
                                              void* __restrict__ Cout,
                                              const float* __restrict__ bias,
                                              unsigned short* __restrict__ qs,
                                              unsigned short* __restrict__ kp,
                                              unsigned short* __restrict__ vp,
                                              int M, int N, int K) {
  constexpr int MR = BM / 32, NR = BN / 32;
  constexpr int CA = BM / 32, CB = BN / 32;        // 16B chunks/thread at BK=64
  constexpr int STAGE_SH = 2 * (BM + BN) * 64;
  constexpr int BOUNCE_SH = MODE == 0 ? BM * BN * 2 : BM * BN;
  constexpr int SMEM_SH = STAGE_SH > BOUNCE_SH ? STAGE_SH : BOUNCE_SH;
  __shared__ __align__(16) unsigned short smem[SMEM_SH];
  const int ASZ = BM * 64, BOFF = 2 * BM * 64, BSZ = BN * 64;

  const int t = threadIdx.x, lane = t & 63, wid = t >> 6;
  const int m0 = blockIdx.y * BM, n0 = blockIdx.x * BN;
  const int wm = (wid >> 1) * (BM / 2), wn = (wid & 1) * (BN / 2);
  const int lr = lane & 15, lg = lane >> 4;
  const unsigned short* Ab = A + (size_t)m0 * K;
  const unsigned short* Bb = Bt + (size_t)n0 * K;
  f32x4 acc[MR][NR] = {};

  const int NT = K / 64;
  auto stage = [&](int buf, int kt) {
#pragma unroll
    for (int c = 0; c < CA; c++) {
      int f = t + 256 * c;
      int row = f >> 3, ch = f & 7;
      gll16(Ab + (size_t)row * K + kt + ((ch ^ (row & 7)) << 3),
            &smem[buf * ASZ + f * 8]);
    }
#pragma unroll
    for (int c = 0; c < CB; c++) {
      int f = t + 256 * c;
      int row = f >> 3, ch = f & 7;
      gll16(Bb + (size_t)row * K + kt + ((ch ^ (row & 7)) << 3),
            &smem[BOFF + buf * BSZ + f * 8]);
    }
  };

  stage(0, 0);
  int buf = 0;
  for (int it = 0; it < NT; ++it) {
    __syncthreads();
    if (it + 1 < NT) stage(buf ^ 1, (it + 1) * 64);
    const unsigned short* Ap = &smem[buf * ASZ];
    const unsigned short* Bp = &smem[BOFF + buf * BSZ];
#pragma unroll
    for (int sl = 0; sl < 2; sl++) {
      const int cs = sl * 4 + lg;                  // 16B chunk within the row
      short8 af[MR], bfv[NR];
#pragma unroll
      for (int i = 0; i < MR; i++) {
        int row = wm + i * 16 + lr;
        af[i] = *(const short8*)&Ap[row * 64 + ((cs ^ (row & 7)) << 3)];
      }
#pragma unroll
      for (int i = 0; i < NR; i++) {
        int row = wn + i * 16 + lr;
        bfv[i] = *(const short8*)&Bp[row * 64 + ((cs ^ (row & 7)) << 3)];
      }
#pragma unroll
      for (int mi = 0; mi < MR; mi++)
#pragma unroll
        for (int ni = 0; ni < NR; ni++)
          acc[mi][ni] = __builtin_amdgcn_mfma_f32_16x16x32_bf16(af[mi], bfv[ni], acc[mi][ni], 0, 0, 0);
    }
    buf ^= 1;
  }

  if (MODE == 0) {
    // ---- f32 bounce: [BM][BN] f32, coalesced float4 stores + bias ----
    __syncthreads();
    float* ft = (float*)smem;
#pragma unroll
    for (int mi = 0; mi < MR; mi++)
#pragma unroll
      for (int ni = 0; ni < NR; ni++)
#pragma unroll
        for (int j = 0; j < 4; j++)
          ft[(wm + mi * 16 + lg * 4 + j) * BN + wn + ni * 16 + lr] = acc[mi][ni][j];
    __syncthreads();
#pragma unroll
    for (int i = 0; i < BM * BN / 1024; i++) {
      int s = t + 256 * i;
      int row = s / (BN / 4), ch = s % (BN / 4);
      float4 v = *(const float4*)&ft[row * BN + ch * 4];
      float4 bv = *(const float4*)&bias[n0 + ch * 4];
      v.x += bv.x; v.y += bv.y; v.z += bv.z; v.w += bv.w;
      *(float4*)&((float*)Cout)[(size_t)(m0 + row) * N + n0 + ch * 4] = v;
    }
  } else {
    // ---- swizzled bf16 bounce [BM][64]: u16 idx = row*64 + ((c ^ ((row>>3)&7))*8 + (col&7))
    __syncthreads();
#pragma unroll
    for (int mi = 0; mi < MR; mi++)
#pragma unroll
      for (int ni = 0; ni < NR; ni++)
#pragma unroll
        for (int j = 0; j < 4; j++) {
          int row = wm + mi * 16 + lg * 4 + j;
          int col = wn + ni * 16 + lr;
          smem[row * 64 + (((col >> 3) ^ ((row >> 3) & 7)) << 3) + (col & 7)] =
              f2bf(acc[mi][ni][j]);
        }
    __syncthreads();

    const int b_ = m0 >> 11;
    const int posb = m0 & 2047;
    const int h = n0 / 192, seg = (n0 % 192) >> 6;
    if (seg < 2) {
      unsigned short* dst = (seg == 0)
          ? qs + ((size_t)(b_ * 8 + h) * 2048 + posb) * 64
          : kp + ((size_t)(b_ * 8 + h) * 2112 + 32 + posb) * 64;
#pragma unroll
      for (int i = 0; i < BM / 32; i++) {
        int s = t + 256 * i;              // BM rows x 8 chunks
        int row = s >> 3, ch = s & 7;
        int src = row * 64 + ((ch ^ ((row >> 3) & 7)) << 3);
        *(ushort8_t*)&dst[s * 8] = *(const ushort8_t*)&smem[src];
      }
    } else {
      unsigned short* dst = vp + (size_t)(b_ * 8 + h) * 64 * 2112;
#pragma unroll
      for (int i = 0; i < BM / 32; i++) {
        int s = t + 256 * i;              // dl 0..63, pc 0..BM/8-1
        int dl = s / (BM / 8), pc = s % (BM / 8);
        ushort8_t v;
#pragma unroll
        for (int j = 0; j < 8; j++) {
          int row = pc * 8 + j;
          v[j] = smem[row * 64 + ((((dl >> 3) ^ (pc & 7)) << 3)) + (dl & 7)];
        }
        *(ushort8_t*)&dst[(size_t)dl * 2112 + 32 + posb + pc * 8] = v;
      }
    }
  }
}

// ---------------- windowed attention: 128-q blocks, 8 waves, LDS-staged ------
__global__ __launch_bounds__(512) void k_attn(const unsigned short* __restrict__ Qs,
                                              const unsigned short* __restrict__ Kp,
                                              const unsigned short* __restrict__ Vp,
                                              unsigned short* __restrict__ attnb) {
  __shared__ __align__(16) unsigned short Kt[192 * 64];  // pos-local x d, swz (24 KB)
  __shared__ __align__(16) unsigned short Vt[64 * 256];  // d x pos-local, swz (32 KB)
  __shared__ __align__(16) unsigned short Qt[128 * 64];  // q-local x d, swz  (16 KB)
  const int t = threadIdx.x, lane = t & 63, w = t >> 6;   // w 0..7
  const int blk = blockIdx.x;
  const int sbi = blk & 15, h = (blk >> 4) & 7, b = blk >> 7;
  const int sb = sbi * 128;
  const int bh = b * 8 + h;
  const int lr = lane & 15, lg = lane >> 4;

  {  // stage K: Kp idx sb..sb+191 (= global pos sb-32..sb+159)
    const unsigned short* src = Kp + ((size_t)bh * 2112 + sb) * 64;
#pragma unroll
    for (int i = 0; i < 3; i++) {
      int s = t + 512 * i, row = s >> 3, c = s & 7;
      gll16(src + row * 64 + (c ^ (row & 7)) * 8, &Kt[s * 8]);
    }
  }
  {  // stage V: Vp cols sb..sb+255 (= global pos sb-32..sb+223)
    const unsigned short* src = Vp + (size_t)bh * 64 * 2112 + sb;
#pragma unroll
    for (int i = 0; i < 4; i++) {
      int s = t + 512 * i, d = s >> 5, c = s & 31;
      gll16(src + (size_t)d * 2112 + (c ^ (d & 7)) * 8, &Vt[s * 8]);
    }
  }
  {  // stage Q: rows sb..sb+127
    const unsigned short* src = Qs + ((size_t)bh * 2048 + sb) * 64;
#pragma unroll
    for (int i = 0; i < 2; i++) {
      int s = t + 512 * i, row = s >> 3, c = s & 7;
      gll16(src + row * 64 + (c ^ (row & 7)) * 8, &Qt[s * 8]);
    }
  }
  __syncthreads();

  const int sw = (lr & 7) << 3;  // u16 read-XOR (16B chunks); rows are 16-aligned
                                 // per wave so row&7 == lr&7 everywhere below.

  short8 qb[2];
#pragma unroll
  for (int ks = 0; ks < 2; ks++)
    qb[ks] = *(const short8*)&Qt[(w * 16 + lr) * 64 + ((ks * 32 + lg * 8) ^ sw)];

  // S^T: col = q = lr, row = pos_local(rel s0-32) = ct*16 + lg*4 + j
  f32x4 sc[5] = {};
#pragma unroll
  for (int ct = 0; ct < 5; ct++) {
#pragma unroll
    for (int ks = 0; ks < 2; ks++) {
      short8 ka = *(const short8*)&Kt[(w * 16 + ct * 16 + lr) * 64 + ((ks * 32 + lg * 8) ^ sw)];
      sc[ct] = __builtin_amdgcn_mfma_f32_16x16x32_bf16(ka, qb[ks], sc[ct], 0, 0, 0);
    }
  }

  float mx = -1e30f;
#pragma unroll
  for (int ct = 0; ct < 5; ct++)
#pragma unroll
    for (int j = 0; j < 4; j++) {
      int c2 = ct * 16 + lg * 4 + j;
      sc[ct][j] = (c2 >= lr && c2 <= lr + 64) ? sc[ct][j] * 0.125f : -1e30f;
      mx = fmaxf(mx, sc[ct][j]);
    }
  mx = fmaxf(mx, __shfl_xor(mx, 16, 64));
  mx = fmaxf(mx, __shfl_xor(mx, 32, 64));

  float pn[5][4];
  float sum = 0.0f;
#pragma unroll
  for (int ct = 0; ct < 5; ct++)
#pragma unroll
    for (int j = 0; j < 4; j++) {
      pn[ct][j] = __expf(sc[ct][j] - mx);
      sum += pn[ct][j];
    }
  sum += __shfl_xor(sum, 16, 64);
  sum += __shfl_xor(sum, 32, 64);
  float inv = 1.0f / sum;

  unsigned int w01[5], w23[5];
#pragma unroll
  for (int ct = 0; ct < 5; ct++) {
    w01[ct] = (unsigned int)f2bf(pn[ct][0] * inv) | ((unsigned int)f2bf(pn[ct][1] * inv) << 16);
    w23[ct] = (unsigned int)f2bf(pn[ct][2] * inv) | ((unsigned int)f2bf(pn[ct][3] * inv) << 16);
  }

  f32x4 oa[4] = {};
  const int h2 = lg & 1, tl = lg >> 1;
  const int sA = 32 * h2 + lr, sB = sA + 16;
#pragma unroll
  for (int ks = 0; ks < 3; ks++) {
    const int T0 = 2 * ks;
    const int T1 = (2 * ks + 1 < 5) ? (2 * ks + 1) : 4;
    unsigned int a0 = __shfl((int)w01[T0], sA, 64), a1 = __shfl((int)w23[T0], sA, 64);
    unsigned int a2 = __shfl((int)w01[T0], sB, 64), a3 = __shfl((int)w23[T0], sB, 64);
    unsigned int b0 = __shfl((int)w01[T1], sA, 64), b1 = __shfl((int)w23[T1], sA, 64);
    unsigned int b2 = __shfl((int)w01[T1], sB, 64), b3 = __shfl((int)w23[T1], sB, 64);
    union { unsigned int u[4]; short8 v; } pb;
    pb.u[0] = tl ? b0 : a0;
    pb.u[1] = tl ? b1 : a1;
    pb.u[2] = tl ? b2 : a2;
    pb.u[3] = tl ? b3 : a3;
    if (ks == 2 && tl) { pb.u[0] = 0; pb.u[1] = 0; pb.u[2] = 0; pb.u[3] = 0; }
    int pofl = w * 16 + ks * 32 + lg * 8;
#pragma unroll
    for (int nt = 0; nt < 4; nt++) {
      short8 va = *(const short8*)&Vt[(nt * 16 + lr) * 256 + (pofl ^ sw)];
      oa[nt] = __builtin_amdgcn_mfma_f32_16x16x32_bf16(va, pb.v, oa[nt], 0, 0, 0);
    }
  }

  const int s0 = sb + w * 16;
#pragma unroll
  for (int nt = 0; nt < 4; nt++) {
    ushort4_t o;
#pragma unroll
    for (int j = 0; j < 4; j++) o[j] = f2bf(oa[nt][j]);
    *(ushort4_t*)&attnb[((size_t)b * S_LEN + s0 + lr) * DMODEL + h * 64 + nt * 16 + lg * 4] = o;
  }
}

// ---------------- launch ----------------
extern "C" void kernel_launch(void* const* d_in, const int* in_sizes, int n_in,
                              void* d_out, int out_size, void* d_ws, size_t ws_size,
                              hipStream_t stream) {
  const float* x    = (const float*)d_in[0];
  const float* Wqkv = (const float*)d_in[1];
  const float* Wout = (const float*)d_in[2];
  const float* bout = (const float*)d_in[3];
  char* ws = (char*)d_ws;
  unsigned short* xb    = (unsigned short*)(ws + 0);         // 4096x512 bf16 (4 MB)
  unsigned short* wqkvt = (unsigned short*)(ws + 4194304);   // 1536x512 bf16 (1.5 MB)
  unsigned short* woutt = (unsigned short*)(ws + 5767168);   // 512x512 bf16  (0.5 MB)
  unsigned short* Qs    = (unsigned short*)(ws + 6291456);   // [16][2048][64] (4 MB)
  unsigned short* Kp    = (unsigned short*)(ws + 10485760);  // [16][2112][64] (4.125 MB)
  unsigned short* Vp    = (unsigned short*)(ws + 14811136);  // [16][64][2112] (4.125 MB + slack)
  unsigned short* attnb = (unsigned short*)(ws + 19922944);  // 4096x512 bf16 (4 MB)

  hipLaunchKernelGGL(k_prep, dim3(2080), dim3(256), 0, stream,
                     x, xb, Wqkv, wqkvt, Wout, woutt, Kp, Vp);
  hipLaunchKernelGGL((k_gemm<128, 64, 1>), dim3(24, 32), dim3(256), 0, stream,
                     xb, wqkvt, nullptr, (const float*)nullptr, Qs, Kp, Vp, 4096, 1536, 512);
  hipLaunchKernelGGL(k_attn, dim3(256), dim3(512), 0, stream, Qs, Kp, Vp, attnb);
  hipLaunchKernelGGL((k_gemm<64, 64, 0>), dim3(8, 64), dim3(256), 0, stream,
                     attnb, woutt, d_out, bout,
                     (unsigned short*)nullptr, (unsigned short*)nullptr,
                     (unsigned short*)nullptr, 4096, 512, 512);
}